// Round 1
// baseline (1122.354 us; speedup 1.0000x reference)
//
#include <hip/hip_runtime.h>
#include <hip/hip_bf16.h>
#include <cstdint>
#include <cstddef>

using bf16 = __hip_bfloat16;
typedef __attribute__((ext_vector_type(8))) short short8;
typedef __attribute__((ext_vector_type(4))) short short4v;
typedef __attribute__((ext_vector_type(4))) float f32x4;

#define MFMA16(a,b,c) __builtin_amdgcn_mfma_f32_16x16x32_bf16((a),(b),(c),0,0,0)

constexpr int S  = 2048;
constexpr int H  = 4096;
constexpr int D  = 128;

static __device__ __forceinline__ short bfbits(float f) {
  bf16 b = __float2bfloat16(f);
  return __builtin_bit_cast(short, b);
}

static __device__ __forceinline__ void gload16(const void* g, void* l) {
  __builtin_amdgcn_global_load_lds((const __attribute__((address_space(1))) void*)g,
                                   (__attribute__((address_space(3))) void*)l, 16, 0, 0);
}

// ---------------- RoPE cos/sin table: [S][64] float2 ----------------
__global__ void k_rope_table(float2* __restrict__ rt) {
  int tid = blockIdx.x * 256 + threadIdx.x;     // S*64 = 131072
  if (tid >= S * 64) return;
  int s = tid >> 6, j = tid & 63;
  float inv = exp2f(-(float)j * (13.287712379549449f / 64.f)); // 10000^(-j/64)
  float a = (float)s * inv;
  rt[tid] = make_float2(cosf(a), sinf(a));
}

// ---------------- cast hidden fp32 -> bf16 ----------------
__global__ void k_cast_x(const float4* __restrict__ x, short4v* __restrict__ xb) {
  int tid = blockIdx.x * 256 + threadIdx.x;     // S*H/4
  float4 v = x[tid];
  short4v o = { bfbits(v.x), bfbits(v.y), bfbits(v.z), bfbits(v.w) };
  xb[tid] = o;
}

// ---------------- GPTQ int4 dequant -> W^T bf16 [N][K] ----------------
__global__ void k_dequant(const unsigned* __restrict__ qw, const unsigned* __restrict__ qz,
                          const float* __restrict__ sc, bf16* __restrict__ wt,
                          int N, int K) {
  long tid = (long)blockIdx.x * 256 + threadIdx.x;   // over (K/8) * N
  if (tid >= (long)(K >> 3) * N) return;
  int k8 = (int)(tid / N);
  int n  = (int)(tid % N);
  int g  = k8 >> 4;                      // (k8*8)/128
  unsigned q  = qw[tid];                 // qweight[k8][n]
  unsigned zq = qz[g * (N >> 3) + (n >> 3)];
  float z = (float)(((zq >> ((n & 7) * 4)) & 15u) + 1u);
  float s = sc[g * N + n];
  short8 o;
#pragma unroll
  for (int i = 0; i < 8; i++) {
    float w = (float)((q >> (4 * i)) & 15u);
    o[i] = bfbits((w - z) * s);
  }
  *(short8*)&wt[(size_t)n * K + (k8 << 3)] = o;
}

// ---------------- bf16 MFMA GEMM: C[M,N] = A[M,K] @ Bt[N,K]^T ----------------
// EPI 0: QKV + fused RoPE -> Q[h][s][d], K[h][s][d], VT[h][d][s]
// EPI 1: plain fp32 store to outf[M][N]
template<int EPI>
__global__ __launch_bounds__(256, 2)
void k_gemm(const bf16* __restrict__ A, const bf16* __restrict__ Bt, int K, int N,
            float* __restrict__ outf,
            bf16* __restrict__ Qv, bf16* __restrict__ Kv, bf16* __restrict__ VT,
            const float2* __restrict__ rope)
{
  __shared__ __align__(16) bf16 sA[128 * 32];
  __shared__ __align__(16) bf16 sB[128 * 32];
  const int t = threadIdx.x;
  const int wid = t >> 6, lane = t & 63;
  const int la = lane & 15, lb = lane >> 4;
  const int m0 = blockIdx.y * 128, n0 = blockIdx.x * 128;

  f32x4 acc[2][8] = {};

  const bf16* gA0 = A  + (size_t)(m0 + (t >> 2))      * K + (t & 3) * 8;
  const bf16* gA1 = A  + (size_t)(m0 + (t >> 2) + 64) * K + (t & 3) * 8;
  const bf16* gB0 = Bt + (size_t)(n0 + (t >> 2))      * K + (t & 3) * 8;
  const bf16* gB1 = Bt + (size_t)(n0 + (t >> 2) + 64) * K + (t & 3) * 8;
  bf16* lA0 = &sA[wid * 512];
  bf16* lA1 = &sA[wid * 512 + 2048];
  bf16* lB0 = &sB[wid * 512];
  bf16* lB1 = &sB[wid * 512 + 2048];

  for (int k0 = 0; k0 < K; k0 += 32) {
    gload16(gA0 + k0, lA0);
    gload16(gA1 + k0, lA1);
    gload16(gB0 + k0, lB0);
    gload16(gB1 + k0, lB1);
    __syncthreads();
    short8 a0 = *(const short8*)&sA[(wid * 32      + la) * 32 + lb * 8];
    short8 a1 = *(const short8*)&sA[(wid * 32 + 16 + la) * 32 + lb * 8];
#pragma unroll
    for (int nf = 0; nf < 8; nf++) {
      short8 b = *(const short8*)&sB[(nf * 16 + la) * 32 + lb * 8];
      acc[0][nf] = MFMA16(a0, b, acc[0][nf]);
      acc[1][nf] = MFMA16(a1, b, acc[1][nf]);
    }
    __syncthreads();
  }

  if constexpr (EPI == 1) {
#pragma unroll
    for (int mi = 0; mi < 2; mi++)
#pragma unroll
      for (int nf = 0; nf < 8; nf++)
#pragma unroll
        for (int r = 0; r < 4; r++) {
          int row = m0 + wid * 32 + mi * 16 + lb * 4 + r;
          int col = n0 + nf * 16 + la;
          outf[(size_t)row * N + col] = acc[mi][nf][r];
        }
  } else {
    int typ = n0 >> 12;            // 0=q, 1=k, 2=v
    int h   = (n0 & 4095) >> 7;
    if (typ < 2) {
      bf16* dst = (typ == 0 ? Qv : Kv) + (size_t)h * S * D;
#pragma unroll
      for (int mi = 0; mi < 2; mi++)
#pragma unroll
        for (int nf = 0; nf < 4; nf++)
#pragma unroll
          for (int r = 0; r < 4; r++) {
            int srow = m0 + wid * 32 + mi * 16 + lb * 4 + r;
            int d = nf * 16 + la;                       // 0..63
            float x  = acc[mi][nf][r];
            float xp = acc[mi][nf + 4][r];              // d+64 partner
            float2 cs = rope[srow * 64 + d];
            dst[(size_t)srow * D + d]      = __float2bfloat16(x * cs.x - xp * cs.y);
            dst[(size_t)srow * D + d + 64] = __float2bfloat16(xp * cs.x + x * cs.y);
          }
    } else {
      bf16* dst = VT + (size_t)h * D * S;   // [d][s]
#pragma unroll
      for (int mi = 0; mi < 2; mi++)
#pragma unroll
        for (int nf = 0; nf < 8; nf++) {
          int d  = nf * 16 + la;
          int s0 = m0 + wid * 32 + mi * 16 + lb * 4;
          short4v o = { bfbits(acc[mi][nf][0]), bfbits(acc[mi][nf][1]),
                        bfbits(acc[mi][nf][2]), bfbits(acc[mi][nf][3]) };
          *(short4v*)&dst[(size_t)d * S + s0] = o;
        }
    }
  }
}

// ---------------- causal flash attention ----------------
// grid (32 q-tiles, 32 heads), 256 thr = 4 waves, wave owns 16 q rows.
__global__ __launch_bounds__(256, 2)
void k_attn(const bf16* __restrict__ Qv, const bf16* __restrict__ Kvp,
            const bf16* __restrict__ VT, bf16* __restrict__ AO)
{
  __shared__ __align__(16) bf16 P[4][16][72];   // padded: stride 144 B
  const int t = threadIdx.x, wid = t >> 6, lane = t & 63;
  const int la = lane & 15, lb = lane >> 4;
  const int h = blockIdx.y, bq = blockIdx.x;
  const int q0 = bq * 64 + wid * 16;
  const bf16* Qh = Qv  + (size_t)h * S * D;
  const bf16* Kh = Kvp + (size_t)h * S * D;
  const bf16* Vh = VT  + (size_t)h * D * S;

  short8 qf[4];
#pragma unroll
  for (int ks = 0; ks < 4; ks++)
    qf[ks] = *(const short8*)&Qh[(size_t)(q0 + la) * D + ks * 32 + lb * 8];

  f32x4 o[8] = {};
  float mrow[4] = {-1e30f, -1e30f, -1e30f, -1e30f};
  float lrow[4] = {0.f, 0.f, 0.f, 0.f};
  const float smscale = 0.08838834764831845f;   // 1/sqrt(128)

  for (int kt = 0; kt <= bq; kt++) {
    const int kv0 = kt * 64;
    f32x4 sv[4] = {};
#pragma unroll
    for (int ks = 0; ks < 4; ks++) {
#pragma unroll
      for (int kf = 0; kf < 4; kf++) {
        short8 kb = *(const short8*)&Kh[(size_t)(kv0 + kf * 16 + la) * D + ks * 32 + lb * 8];
        sv[kf] = MFMA16(qf[ks], kb, sv[kf]);
      }
    }
    const bool needmask = (kv0 + 63 > q0);
#pragma unroll
    for (int kf = 0; kf < 4; kf++)
#pragma unroll
      for (int r = 0; r < 4; r++) {
        float v = sv[kf][r] * smscale;
        if (needmask && (kv0 + kf * 16 + la > q0 + lb * 4 + r)) v = -1e30f;
        sv[kf][r] = v;
      }
    float mnew[4], csc[4], rs[4];
#pragma unroll
    for (int r = 0; r < 4; r++)
      mnew[r] = fmaxf(fmaxf(sv[0][r], sv[1][r]), fmaxf(sv[2][r], sv[3][r]));
#pragma unroll
    for (int off = 1; off < 16; off <<= 1)
#pragma unroll
      for (int r = 0; r < 4; r++) mnew[r] = fmaxf(mnew[r], __shfl_xor(mnew[r], off));
#pragma unroll
    for (int r = 0; r < 4; r++) {
      float mt = fmaxf(mrow[r], mnew[r]);
      csc[r] = __expf(mrow[r] - mt);
      mrow[r] = mt;
      rs[r] = 0.f;
    }
#pragma unroll
    for (int kf = 0; kf < 4; kf++)
#pragma unroll
      for (int r = 0; r < 4; r++) {
        float p = __expf(sv[kf][r] - mrow[r]);
        sv[kf][r] = p;
        rs[r] += p;
      }
#pragma unroll
    for (int off = 1; off < 16; off <<= 1)
#pragma unroll
      for (int r = 0; r < 4; r++) rs[r] += __shfl_xor(rs[r], off);
#pragma unroll
    for (int r = 0; r < 4; r++) lrow[r] = lrow[r] * csc[r] + rs[r];
#pragma unroll
    for (int df = 0; df < 8; df++)
#pragma unroll
      for (int r = 0; r < 4; r++) o[df][r] *= csc[r];
    // P -> LDS (per-wave region, no cross-wave sync needed)
#pragma unroll
    for (int kf = 0; kf < 4; kf++)
#pragma unroll
      for (int r = 0; r < 4; r++)
        P[wid][lb * 4 + r][kf * 16 + la] = __float2bfloat16(sv[kf][r]);
    asm volatile("s_waitcnt lgkmcnt(0)" ::: "memory");
    short8 pa0 = *(const short8*)&P[wid][la][lb * 8];
    short8 pa1 = *(const short8*)&P[wid][la][32 + lb * 8];
#pragma unroll
    for (int df = 0; df < 8; df++) {
      short8 vb0 = *(const short8*)&Vh[(size_t)(df * 16 + la) * S + kv0 + lb * 8];
      o[df] = MFMA16(pa0, vb0, o[df]);
      short8 vb1 = *(const short8*)&Vh[(size_t)(df * 16 + la) * S + kv0 + 32 + lb * 8];
      o[df] = MFMA16(pa1, vb1, o[df]);
    }
  }
#pragma unroll
  for (int r = 0; r < 4; r++) lrow[r] = 1.f / lrow[r];
#pragma unroll
  for (int df = 0; df < 8; df++)
#pragma unroll
    for (int r = 0; r < 4; r++) {
      int srow = q0 + lb * 4 + r;
      int d = df * 16 + la;
      AO[(size_t)srow * H + h * D + d] = __float2bfloat16(o[df][r] * lrow[r]);
    }
}

extern "C" void kernel_launch(void* const* d_in, const int* in_sizes, int n_in,
                              void* d_out, int out_size, void* d_ws, size_t ws_size,
                              hipStream_t stream) {
  const float*    X      = (const float*)d_in[0];
  const unsigned* qw_qkv = (const unsigned*)d_in[1];
  const unsigned* qz_qkv = (const unsigned*)d_in[2];
  const float*    sc_qkv = (const float*)d_in[3];
  const unsigned* qw_o   = (const unsigned*)d_in[4];
  const unsigned* qz_o   = (const unsigned*)d_in[5];
  const float*    sc_o   = (const float*)d_in[6];
  float* out = (float*)d_out;

  // workspace layout (bytes)
  //   0         : Wt      100,663,296  (qkv W^T, later o W^T)
  //   100663296 : Xb       16,777,216  (X bf16; reused as attention output)
  //   117440512 : Q        16,777,216
  //   134217728 : K        16,777,216
  //   150994944 : VT       16,777,216
  //   167772160 : rope      1,048,576
  if (ws_size < 168820736ULL) return;
  char* ws = (char*)d_ws;
  bf16*   Wt = (bf16*)(ws);
  bf16*   Xb = (bf16*)(ws + 100663296);
  bf16*   Qv = (bf16*)(ws + 117440512);
  bf16*   Kv = (bf16*)(ws + 134217728);
  bf16*   VT = (bf16*)(ws + 150994944);
  float2* rt = (float2*)(ws + 167772160);
  bf16*   AO = Xb;

  k_rope_table<<<512, 256, 0, stream>>>(rt);
  k_cast_x<<<(S * H / 4) / 256, 256, 0, stream>>>((const float4*)X, (short4v*)Xb);
  k_dequant<<<(512 * 12288) / 256, 256, 0, stream>>>(qw_qkv, qz_qkv, sc_qkv, Wt, 12288, 4096);
  k_gemm<0><<<dim3(96, 16), 256, 0, stream>>>(Xb, Wt, 4096, 12288, nullptr, Qv, Kv, VT, rt);
  k_dequant<<<(512 * 4096) / 256, 256, 0, stream>>>(qw_o, qz_o, sc_o, Wt, 4096, 4096);
  k_attn<<<dim3(32, 32), 256, 0, stream>>>(Qv, Kv, VT, AO);
  k_gemm<1><<<dim3(32, 16), 256, 0, stream>>>(AO, Wt, 4096, 4096, out, nullptr, nullptr, nullptr, nullptr);
}

// Round 2
// 517.250 us; speedup vs baseline: 2.1698x; 2.1698x over previous
//
#include <hip/hip_runtime.h>
#include <hip/hip_bf16.h>
#include <cstdint>
#include <cstddef>

using bf16 = __hip_bfloat16;
typedef __attribute__((ext_vector_type(8))) short short8;
typedef __attribute__((ext_vector_type(4))) short short4v;
typedef __attribute__((ext_vector_type(4))) float f32x4;

#define MFMA16(a,b,c) __builtin_amdgcn_mfma_f32_16x16x32_bf16((a),(b),(c),0,0,0)

constexpr int S  = 2048;
constexpr int H  = 4096;
constexpr int D  = 128;

static __device__ __forceinline__ short bfbits(float f) {
  bf16 b = __float2bfloat16(f);
  return __builtin_bit_cast(short, b);
}

static __device__ __forceinline__ void gload16(const void* g, void* l) {
  __builtin_amdgcn_global_load_lds((const __attribute__((address_space(1))) void*)g,
                                   (__attribute__((address_space(3))) void*)l, 16, 0, 0);
}

// ---------------- RoPE cos/sin table: [S][64] float2 ----------------
__global__ void k_rope_table(float2* __restrict__ rt) {
  int tid = blockIdx.x * 256 + threadIdx.x;     // S*64 = 131072
  if (tid >= S * 64) return;
  int s = tid >> 6, j = tid & 63;
  float inv = exp2f(-(float)j * (13.287712379549449f / 64.f)); // 10000^(-j/64)
  float a = (float)s * inv;
  rt[tid] = make_float2(cosf(a), sinf(a));
}

// ---------------- cast hidden fp32 -> bf16 ----------------
__global__ void k_cast_x(const float4* __restrict__ x, short4v* __restrict__ xb) {
  int tid = blockIdx.x * 256 + threadIdx.x;     // S*H/4
  float4 v = x[tid];
  short4v o = { bfbits(v.x), bfbits(v.y), bfbits(v.z), bfbits(v.w) };
  xb[tid] = o;
}

// ---------------- GPTQ int4 dequant -> W^T bf16 [N][K] ----------------
__global__ void k_dequant(const unsigned* __restrict__ qw, const unsigned* __restrict__ qz,
                          const float* __restrict__ sc, bf16* __restrict__ wt,
                          int N, int K) {
  long tid = (long)blockIdx.x * 256 + threadIdx.x;   // over (K/8) * N
  if (tid >= (long)(K >> 3) * N) return;
  int k8 = (int)(tid / N);
  int n  = (int)(tid % N);
  int g  = k8 >> 4;                      // (k8*8)/128
  unsigned q  = qw[tid];                 // qweight[k8][n]
  unsigned zq = qz[g * (N >> 3) + (n >> 3)];
  float z = (float)(((zq >> ((n & 7) * 4)) & 15u) + 1u);
  float s = sc[g * N + n];
  short8 o;
#pragma unroll
  for (int i = 0; i < 8; i++) {
    float w = (float)((q >> (4 * i)) & 15u);
    o[i] = bfbits((w - z) * s);
  }
  *(short8*)&wt[(size_t)n * K + (k8 << 3)] = o;
}

// ---------------- bf16 MFMA GEMM: C[M,N] = A[M,K] @ Bt[N,K]^T ----------------
template<int EPI>
__global__ __launch_bounds__(256, 2)
void k_gemm(const bf16* __restrict__ A, const bf16* __restrict__ Bt, int K, int N,
            float* __restrict__ outf,
            bf16* __restrict__ Qv, bf16* __restrict__ Kv, bf16* __restrict__ VT,
            const float2* __restrict__ rope)
{
  __shared__ __align__(16) bf16 sA[128 * 32];
  __shared__ __align__(16) bf16 sB[128 * 32];
  const int t = threadIdx.x;
  const int wid = t >> 6, lane = t & 63;
  const int la = lane & 15, lb = lane >> 4;
  const int m0 = blockIdx.y * 128, n0 = blockIdx.x * 128;

  f32x4 acc[2][8] = {};

  const bf16* gA0 = A  + (size_t)(m0 + (t >> 2))      * K + (t & 3) * 8;
  const bf16* gA1 = A  + (size_t)(m0 + (t >> 2) + 64) * K + (t & 3) * 8;
  const bf16* gB0 = Bt + (size_t)(n0 + (t >> 2))      * K + (t & 3) * 8;
  const bf16* gB1 = Bt + (size_t)(n0 + (t >> 2) + 64) * K + (t & 3) * 8;
  bf16* lA0 = &sA[wid * 512];
  bf16* lA1 = &sA[wid * 512 + 2048];
  bf16* lB0 = &sB[wid * 512];
  bf16* lB1 = &sB[wid * 512 + 2048];

  for (int k0 = 0; k0 < K; k0 += 32) {
    gload16(gA0 + k0, lA0);
    gload16(gA1 + k0, lA1);
    gload16(gB0 + k0, lB0);
    gload16(gB1 + k0, lB1);
    __syncthreads();
    short8 a0 = *(const short8*)&sA[(wid * 32      + la) * 32 + lb * 8];
    short8 a1 = *(const short8*)&sA[(wid * 32 + 16 + la) * 32 + lb * 8];
#pragma unroll
    for (int nf = 0; nf < 8; nf++) {
      short8 b = *(const short8*)&sB[(nf * 16 + la) * 32 + lb * 8];
      acc[0][nf] = MFMA16(a0, b, acc[0][nf]);
      acc[1][nf] = MFMA16(a1, b, acc[1][nf]);
    }
    __syncthreads();
  }

  if constexpr (EPI == 1) {
#pragma unroll
    for (int mi = 0; mi < 2; mi++)
#pragma unroll
      for (int nf = 0; nf < 8; nf++)
#pragma unroll
        for (int r = 0; r < 4; r++) {
          int row = m0 + wid * 32 + mi * 16 + lb * 4 + r;
          int col = n0 + nf * 16 + la;
          outf[(size_t)row * N + col] = acc[mi][nf][r];
        }
  } else {
    int typ = n0 >> 12;            // 0=q, 1=k, 2=v
    int h   = (n0 & 4095) >> 7;
    if (typ < 2) {
      bf16* dst = (typ == 0 ? Qv : Kv) + (size_t)h * S * D;
#pragma unroll
      for (int mi = 0; mi < 2; mi++)
#pragma unroll
        for (int nf = 0; nf < 4; nf++)
#pragma unroll
          for (int r = 0; r < 4; r++) {
            int srow = m0 + wid * 32 + mi * 16 + lb * 4 + r;
            int d = nf * 16 + la;                       // 0..63
            float x  = acc[mi][nf][r];
            float xp = acc[mi][nf + 4][r];              // d+64 partner
            float2 cs = rope[srow * 64 + d];
            dst[(size_t)srow * D + d]      = __float2bfloat16(x * cs.x - xp * cs.y);
            dst[(size_t)srow * D + d + 64] = __float2bfloat16(xp * cs.x + x * cs.y);
          }
    } else {
      bf16* dst = VT + (size_t)h * D * S;   // [d][s]
#pragma unroll
      for (int mi = 0; mi < 2; mi++)
#pragma unroll
        for (int nf = 0; nf < 8; nf++) {
          int d  = nf * 16 + la;
          int s0 = m0 + wid * 32 + mi * 16 + lb * 4;
          short4v o = { bfbits(acc[mi][nf][0]), bfbits(acc[mi][nf][1]),
                        bfbits(acc[mi][nf][2]), bfbits(acc[mi][nf][3]) };
          *(short4v*)&dst[(size_t)d * S + s0] = o;
        }
    }
  }
}

// ---------------- causal flash attention, paired q-tiles + LDS KV pipeline ----
// grid (16 pair-blocks, 32 heads), 256 thr = 4 waves, wave owns 16 q rows of
// each of two q-tiles (i and 31-i). KV tiles staged in LDS (double-buffered,
// XOR-swizzled), shared by all 4 waves.
struct AttnCtx {
  int la, lb, q_wave_off;
  const float smscale = 0.08838834764831845f;
};

__device__ __forceinline__ void tile_step(
    const short8 (&qf)[4], f32x4 (&o)[8], float (&mrow)[4], float (&lrow)[4],
    int q0t, int kv0, const char* kld, const char* vld,
    bf16 (*Pw)[72], int la, int lb)
{
  const float smscale = 0.08838834764831845f;   // 1/sqrt(128)
  f32x4 sv[4] = {};
  __builtin_amdgcn_s_setprio(1);
#pragma unroll
  for (int ks = 0; ks < 4; ks++) {
#pragma unroll
    for (int kf = 0; kf < 4; kf++) {
      int row = kf * 16 + la;
      short8 kb = *(const short8*)(kld + row * 256 + ((ks * 64 + lb * 16) ^ ((row & 7) << 4)));
      sv[kf] = MFMA16(qf[ks], kb, sv[kf]);
    }
  }
  __builtin_amdgcn_s_setprio(0);
  const bool needmask = (kv0 + 63 > q0t);
#pragma unroll
  for (int kf = 0; kf < 4; kf++)
#pragma unroll
    for (int r = 0; r < 4; r++) {
      float v = sv[kf][r] * smscale;
      if (needmask && (kv0 + kf * 16 + la > q0t + lb * 4 + r)) v = -1e30f;
      sv[kf][r] = v;
    }
  float mnew[4], csc[4], rs[4];
#pragma unroll
  for (int r = 0; r < 4; r++)
    mnew[r] = fmaxf(fmaxf(sv[0][r], sv[1][r]), fmaxf(sv[2][r], sv[3][r]));
#pragma unroll
  for (int off = 1; off < 16; off <<= 1)
#pragma unroll
    for (int r = 0; r < 4; r++) mnew[r] = fmaxf(mnew[r], __shfl_xor(mnew[r], off));
#pragma unroll
  for (int r = 0; r < 4; r++) {
    float mt = fmaxf(mrow[r], mnew[r]);
    csc[r] = __expf(mrow[r] - mt);
    mrow[r] = mt;
    rs[r] = 0.f;
  }
#pragma unroll
  for (int kf = 0; kf < 4; kf++)
#pragma unroll
    for (int r = 0; r < 4; r++) {
      float p = __expf(sv[kf][r] - mrow[r]);
      sv[kf][r] = p;
      rs[r] += p;
    }
#pragma unroll
  for (int off = 1; off < 16; off <<= 1)
#pragma unroll
    for (int r = 0; r < 4; r++) rs[r] += __shfl_xor(rs[r], off);
#pragma unroll
  for (int r = 0; r < 4; r++) lrow[r] = lrow[r] * csc[r] + rs[r];
#pragma unroll
  for (int df = 0; df < 8; df++)
#pragma unroll
    for (int r = 0; r < 4; r++) o[df][r] *= csc[r];
  // P -> per-wave LDS region
#pragma unroll
  for (int kf = 0; kf < 4; kf++)
#pragma unroll
    for (int r = 0; r < 4; r++)
      Pw[lb * 4 + r][kf * 16 + la] = __float2bfloat16(sv[kf][r]);
  asm volatile("s_waitcnt lgkmcnt(0)" ::: "memory");
  __builtin_amdgcn_sched_barrier(0);
  short8 pa0 = *(const short8*)&Pw[la][lb * 8];
  short8 pa1 = *(const short8*)&Pw[la][32 + lb * 8];
  __builtin_amdgcn_s_setprio(1);
#pragma unroll
  for (int df = 0; df < 8; df++) {
    int d = df * 16 + la;
    short8 vb0 = *(const short8*)(vld + d * 128 + ((lb * 16) ^ ((d & 7) << 4)));
    o[df] = MFMA16(pa0, vb0, o[df]);
    short8 vb1 = *(const short8*)(vld + d * 128 + ((64 + lb * 16) ^ ((d & 7) << 4)));
    o[df] = MFMA16(pa1, vb1, o[df]);
  }
  __builtin_amdgcn_s_setprio(0);
}

__global__ __launch_bounds__(256, 2)
void k_attn(const bf16* __restrict__ Qv, const bf16* __restrict__ Kvp,
            const bf16* __restrict__ VT, bf16* __restrict__ AO)
{
  __shared__ __align__(16) char kvs[2][2][16384];   // [dbuf][K/V]
  __shared__ __align__(16) bf16 P[4][16][72];
  const int t = threadIdx.x, wid = t >> 6, lane = t & 63;
  const int la = lane & 15, lb = lane >> 4;
  const int h = blockIdx.y, ip = blockIdx.x;         // 0..15
  const int tA = ip, tB = 31 - ip;
  const int q0A = tA * 64 + wid * 16, q0B = tB * 64 + wid * 16;
  const bf16* Qh = Qv  + (size_t)h * S * D;
  const bf16* Kh = Kvp + (size_t)h * S * D;
  const bf16* Vh = VT  + (size_t)h * D * S;

  short8 qfA[4], qfB[4];
#pragma unroll
  for (int ks = 0; ks < 4; ks++) {
    qfA[ks] = *(const short8*)&Qh[(size_t)(q0A + la) * D + ks * 32 + lb * 8];
    qfB[ks] = *(const short8*)&Qh[(size_t)(q0B + la) * D + ks * 32 + lb * 8];
  }

  f32x4 oA[8] = {}, oB[8] = {};
  float mA[4] = {-1e30f, -1e30f, -1e30f, -1e30f}, lA[4] = {};
  float mB[4] = {-1e30f, -1e30f, -1e30f, -1e30f}, lB[4] = {};

  auto stage = [&](int buf, int kv0) {
#pragma unroll
    for (int i = 0; i < 4; i++) {
      int off = i * 4096 + wid * 1024 + lane * 16;
      int krow = off >> 8, kcol = off & 255;
      const char* ksrc = (const char*)Kh + (size_t)(kv0 + krow) * 256 + (kcol ^ ((krow & 7) << 4));
      gload16(ksrc, &kvs[buf][0][i * 4096 + wid * 1024]);
      int vrow = off >> 7, vcol = off & 127;
      const char* vsrc = (const char*)Vh + (size_t)vrow * (S * 2) + kv0 * 2 + (vcol ^ ((vrow & 7) << 4));
      gload16(vsrc, &kvs[buf][1][i * 4096 + wid * 1024]);
    }
  };

  stage(0, 0);
  __syncthreads();

  const int last = tB;
  for (int kt = 0; kt <= last; kt++) {
    int cur = kt & 1;
    if (kt < last) stage(cur ^ 1, (kt + 1) * 64);
    const char* kld = kvs[cur][0];
    const char* vld = kvs[cur][1];
    int kv0 = kt * 64;
    if (kt <= tA) tile_step(qfA, oA, mA, lA, q0A, kv0, kld, vld, P[wid], la, lb);
    tile_step(qfB, oB, mB, lB, q0B, kv0, kld, vld, P[wid], la, lb);
    __syncthreads();
  }

#pragma unroll
  for (int r = 0; r < 4; r++) { mA[r] = 1.f / lA[r]; mB[r] = 1.f / lB[r]; }
#pragma unroll
  for (int df = 0; df < 8; df++)
#pragma unroll
    for (int r = 0; r < 4; r++) {
      int d = df * 16 + la;
      AO[(size_t)(q0A + lb * 4 + r) * H + h * D + d] = __float2bfloat16(oA[df][r] * mA[r]);
      AO[(size_t)(q0B + lb * 4 + r) * H + h * D + d] = __float2bfloat16(oB[df][r] * mB[r]);
    }
}

extern "C" void kernel_launch(void* const* d_in, const int* in_sizes, int n_in,
                              void* d_out, int out_size, void* d_ws, size_t ws_size,
                              hipStream_t stream) {
  const float*    X      = (const float*)d_in[0];
  const unsigned* qw_qkv = (const unsigned*)d_in[1];
  const unsigned* qz_qkv = (const unsigned*)d_in[2];
  const float*    sc_qkv = (const float*)d_in[3];
  const unsigned* qw_o   = (const unsigned*)d_in[4];
  const unsigned* qz_o   = (const unsigned*)d_in[5];
  const float*    sc_o   = (const float*)d_in[6];
  float* out = (float*)d_out;

  if (ws_size < 168820736ULL) return;
  char* ws = (char*)d_ws;
  bf16*   Wt = (bf16*)(ws);
  bf16*   Xb = (bf16*)(ws + 100663296);
  bf16*   Qv = (bf16*)(ws + 117440512);
  bf16*   Kv = (bf16*)(ws + 134217728);
  bf16*   VT = (bf16*)(ws + 150994944);
  float2* rt = (float2*)(ws + 167772160);
  bf16*   AO = Xb;

  k_rope_table<<<512, 256, 0, stream>>>(rt);
  k_cast_x<<<(S * H / 4) / 256, 256, 0, stream>>>((const float4*)X, (short4v*)Xb);
  k_dequant<<<(512 * 12288) / 256, 256, 0, stream>>>(qw_qkv, qz_qkv, sc_qkv, Wt, 12288, 4096);
  k_gemm<0><<<dim3(96, 16), 256, 0, stream>>>(Xb, Wt, 4096, 12288, nullptr, Qv, Kv, VT, rt);
  k_dequant<<<(512 * 4096) / 256, 256, 0, stream>>>(qw_o, qz_o, sc_o, Wt, 4096, 4096);
  k_attn<<<dim3(16, 32), 256, 0, stream>>>(Qv, Kv, VT, AO);
  k_gemm<1><<<dim3(32, 16), 256, 0, stream>>>(AO, Wt, 4096, 4096, out, nullptr, nullptr, nullptr, nullptr);
}